// Round 10
// baseline (307.928 us; speedup 1.0000x reference)
//
#include <hip/hip_runtime.h>
#include <math.h>

#define B 4
#define CIN 64
#define H 128
#define W 128
#define COUT 128
#define KK 9
#define HW (H*W)

#define WCONV_SZ (CIN*4*72)          // [c][wave][i(8)][tap(9)] offmask weights
#define WBF_COLS 640                 // 4 chunks x 160 (144 real + 16 zero)
#define WBF_SHORTS (COUT*WBF_COLS)
#define LDK 168                      // LDS k-stride (shorts); 336B row stride

typedef __attribute__((ext_vector_type(8))) short short8;
typedef __attribute__((ext_vector_type(4))) float f32x4;
typedef __attribute__((ext_vector_type(2))) float f32x2;
typedef f32x2 __attribute__((aligned(4))) f32x2a;   // align-4 float2 load

__device__ __forceinline__ unsigned short f2bf(float f) {
    unsigned int u = __float_as_uint(f);
    u += 0x7fffu + ((u >> 16) & 1u);
    return (unsigned short)(u >> 16);
}

// ---------------------------------------------------------------------------
// prep: wconv[(c*4+w)*72 + i*9 + t] (f = w*8+i; f>=27 zero), bcat biases.
// Layout is contiguous per (c,wave) so the fused kernel's wave-uniform
// weight reads merge into s_load_dwordx8/16 batches.
// ---------------------------------------------------------------------------
__global__ void prep_kernel(const float* __restrict__ w_off, const float* __restrict__ b_off,
                            const float* __restrict__ w_mask, const float* __restrict__ b_mask,
                            float* __restrict__ wconv, float* __restrict__ bcat)
{
    int idx = blockIdx.x * 256 + threadIdx.x;
    if (idx < WCONV_SZ) {
        int c   = idx / 288;
        int rem = idx % 288;
        int w   = rem / 72;
        int r   = rem % 72;
        int i   = r / 9;
        int t   = r % 9;
        int f   = w * 8 + i;
        float v = 0.f;
        if (f < 18)      v = w_off[(f * CIN + c) * 9 + t];
        else if (f < 27) v = w_mask[((f - 18) * CIN + c) * 9 + t];
        wconv[idx] = v;
    }
    if (blockIdx.x == 0 && threadIdx.x < 32) {
        int f = threadIdx.x;
        float bv = 0.f;
        if (f < 18) bv = b_off[f];
        else if (f < 27) bv = b_mask[f - 18];
        bcat[f] = bv;
    }
}

// ---------------------------------------------------------------------------
// prep_wbf: einsum weights -> bf16, layout [o][cb*160 + tap*16 + ci];
// pad cols [144,160) per chunk are ZERO.
// ---------------------------------------------------------------------------
__global__ void prep_wbf(const float* __restrict__ wgt, short* __restrict__ wbf)
{
    int idx = blockIdx.x * 256 + threadIdx.x;
    if (idx >= WBF_SHORTS) return;
    int o  = idx / WBF_COLS;
    int kp = idx % WBF_COLS;
    int cb = kp / 160, r = kp % 160;
    float v = 0.f;
    if (r < 144) {
        int tap = r >> 4;
        int c   = cb * 16 + (r & 15);
        v = wgt[(o * CIN + c) * KK + tap];
    }
    wbf[idx] = (short)f2bf(v);
}

// ---------------------------------------------------------------------------
// fused: offmask conv (phase A) + deform sample/MFMA (phase B), one block
// per 64-px tile. Phase A computes the 27-filter conv from the SAME staged
// XW windows phase B uses, keeps offs/mask in LDS (aliased into S), so the
// 7 MB offs/mask global round-trip and a whole kernel launch disappear.
//   Phase A layout: lane = pixel, wave = 8-filter group -> x reads are
//   9 ds_read_b32/ch (stride-1, conflict-free); weights are wave-uniform
//   -> s_load scalar path (offmask4-verified mechanism).
//   Phase B: deform6 verbatim; metadata reads offs_l (LDS) not global.
// LDS: XW 13,824 + S 21,504 = 35,328 B -> 4 blocks/CU.
// XCD band swizzle, uniform chunk order (no stagger: R8 lesson).
// ---------------------------------------------------------------------------
__global__ __launch_bounds__(256)
__attribute__((amdgpu_waves_per_eu(4, 4)))
void fused_kernel(
    const float* __restrict__ x, const float* __restrict__ wconv,
    const float* __restrict__ bcat, const short* __restrict__ wbf,
    float* __restrict__ out)
{
    const int bid = blockIdx.x;
    const int T = (bid & 7) * 128 + (bid >> 3);
    const int wo0 = (T & 1) * 64;
    const int ho  = (T >> 1) & 127;
    const int b   = T >> 8;
    const int tid  = threadIdx.x;
    const int lane = tid & 63;
    const int wv   = tid >> 6;
    const int oh   = (wv & 1) * 64;
    const int ph   = (wv >> 1) * 32;
    const int row16 = lane & 15, kq = lane >> 4;

    __shared__ __align__(16) float XW[8 * 6 * 72];    // 13,824 B
    __shared__ __align__(16) short S[64 * LDK];       // 21,504 B
    float* offs_l = (float*)S;                        // phase-A alias: 27*64 f32

    const float* xb = x + (size_t)b * CIN * HW;

    // ---- staging slot precompute (shared by both phases) ----
    int  st_lds[4]; int st_goff[4]; bool st_v[4], st_w[4];
    #pragma unroll
    for (int t = 0; t < 4; ++t) {
        int idx = tid + t * 256;
        st_w[t] = idx < 864;
        int ci = idx / 108, rem = idx % 108, row = rem / 18, q = rem % 18;
        int ys = min(max(ho - 2 + row, 0), H - 1);
        int g0 = wo0 - 4 + q * 4;
        st_lds[t]  = (ci * 6 + row) * 72 + q * 4;
        st_goff[t] = ci * HW + ys * W + g0;
        st_v[t] = st_w[t] && (g0 >= 0) && (g0 <= W - 4);
    }
    f32x4 rg[4];
    auto regload = [&](int h) {
        const float* base = xb + (size_t)h * 8 * HW;
        #pragma unroll
        for (int t = 0; t < 4; ++t) {
            f32x4 v = {0.f, 0.f, 0.f, 0.f};
            if (st_v[t]) v = *(const f32x4*)(base + st_goff[t]);
            rg[t] = v;
        }
    };
    auto regwrite = [&]() {
        #pragma unroll
        for (int t = 0; t < 4; ++t)
            if (st_w[t]) *(f32x4*)&XW[st_lds[t]] = rg[t];
    };

    // =======================================================================
    // Phase A: offmask conv. lane=px, wave=8-filter group.
    // =======================================================================
    const int ws = __builtin_amdgcn_readfirstlane(tid >> 6);  // SGPR wave id
    const int px = lane;
    bool rv0 = ((unsigned)(ho - 1) < (unsigned)H);
    bool rv1 = true;                                   // ho always in [0,H)
    bool rv2 = ((unsigned)(ho + 1) < (unsigned)H);

    float acc27[8];
    #pragma unroll
    for (int i = 0; i < 8; ++i) acc27[i] = 0.f;

    regload(0);
    regwrite();
    __syncthreads();

    #pragma unroll 1
    for (int h = 0; h < 8; ++h) {
        if (h < 7) regload(h + 1);          // next window in flight
        #pragma unroll
        for (int c = 0; c < 8; ++c) {
            float xv[9];
            #pragma unroll
            for (int kx = 0; kx < 3; ++kx) {
                xv[0 + kx] = rv0 ? XW[(c * 6 + 1) * 72 + px + 3 + kx] : 0.f;
                xv[3 + kx] =       XW[(c * 6 + 2) * 72 + px + 3 + kx];
                xv[6 + kx] = rv2 ? XW[(c * 6 + 3) * 72 + px + 3 + kx] : 0.f;
            }
            const float* wp = wconv + (((h * 8 + c) * 4 + ws) * 72);  // uniform
            #pragma unroll
            for (int i = 0; i < 8; ++i) {
                float a = acc27[i];
                #pragma unroll
                for (int t = 0; t < 9; ++t)
                    a += wp[i * 9 + t] * xv[t];
                acc27[i] = a;
            }
        }
        if (h < 7) {
            __syncthreads();                // XW reads done
            regwrite();                     // XW <- half h+1
            __syncthreads();
        }
    }
    (void)rv1;

    // bias + sigmoid -> offs_l (LDS). f = ws*8+i; channels 0..17 = offsets,
    // 18..26 = mask (sigmoid). f>=27 unused.
    #pragma unroll
    for (int i = 0; i < 8; ++i) {
        int f = ws * 8 + i;
        if (f < 27) {
            float v = acc27[i] + bcat[f];
            if (f >= 18) v = 1.f / (1.f + expf(-v));
            offs_l[f * 64 + px] = v;
        }
    }
    __syncthreads();                        // offs_l visible; XW reads done

    // =======================================================================
    // Phase B: deform (metadata from offs_l, then sample + MFMA).
    // =======================================================================
    regload(0);                             // phase-B first window in flight

    int   moff[3][2];
    int   lidx0[3], lidx1[3];
    float wA0[3], wB0[3], wA1[3], wB1[3];
    #pragma unroll
    for (int j = 0; j < 3; ++j) {
        moff[j][0] = 0; moff[j][1] = 0;
        lidx0[j] = -1; lidx1[j] = 0;
        wA0[j] = 0.f; wB0[j] = 0.f; wA1[j] = 0.f; wB1[j] = 0.f;
        int s = tid + j * 256;
        if (s < 576) {
            int k = s >> 6, p = s & 63;
            int wo = wo0 + p;
            int ky = k / 3, kx = k % 3;
            float dy = offs_l[(2 * k) * 64 + p];
            float dx = offs_l[(2 * k + 1) * 64 + p];
            float mk = offs_l[(18 + k) * 64 + p];
            float py  = (float)(ho - 1 + ky) + dy;
            float pxf = (float)(wo - 1 + kx) + dx;
            float fy = floorf(py), fx = floorf(pxf);
            float ly = py - fy, lx = pxf - fx;
            int y0 = (int)fy, x0 = (int)fx;
            int y1 = y0 + 1,  x1 = x0 + 1;
            bool vy0 = (y0 >= 0) && (y0 < H);
            bool vy1 = (y1 >= 0) && (y1 < H);
            bool vx0 = (x0 >= 0) && (x0 < W);
            bool vx1 = (x1 >= 0) && (x1 < W);
            float w0 = (vy0 && vx0) ? (1.f - ly) * (1.f - lx) * mk : 0.f;
            float w1 = (vy0 && vx1) ? (1.f - ly) * lx * mk : 0.f;
            float w2 = (vy1 && vx0) ? ly * (1.f - lx) * mk : 0.f;
            float w3 = (vy1 && vx1) ? ly * lx * mk : 0.f;
            int lc = min(max(x0, 0), W - 2);
            bool sel = (x0 == lc);
            int r0 = min(max(y0, 0), H - 1);
            int r1 = min(max(y1, 0), H - 1);
            moff[j][0] = (r0 * W + lc) * 4;
            moff[j][1] = (r1 * W + lc) * 4;
            wA0[j] = sel ? w0 : w1;  wB0[j] = sel ? w1 : w0;
            wA1[j] = sel ? w2 : w3;  wB1[j] = sel ? w3 : w2;
            int u0 = r0 - (ho - 2);
            int u1 = r1 - (ho - 2);
            int vvv = lc - (wo0 - 4);
            bool fastp = ((unsigned)u0 < 6u) && ((unsigned)u1 < 6u)
                       && ((unsigned)vvv < 71u);
            lidx1[j] = u1 * 72 + vvv;
            lidx0[j] = fastp ? (u0 * 72 + vvv) : -1;
        }
    }
    __syncthreads();                        // all offs_l reads done -> S free

    if (tid < 128) {                        // zero K-pad [144,160)
        short8 z = {0,0,0,0,0,0,0,0};
        *(short8*)&S[(tid >> 1) * LDK + 144 + (tid & 1) * 8] = z;
    }

    f32x4 acc[4][2];
    #pragma unroll
    for (int i = 0; i < 4; ++i)
        #pragma unroll
        for (int j = 0; j < 2; ++j)
            acc[i][j] = (f32x4){0.f, 0.f, 0.f, 0.f};

    auto sample_h = [&](int h, int par) {
        #pragma unroll
        for (int j = 0; j < 3; ++j) {
            int s = tid + j * 256;
            if (s < 576) {
                int k = s >> 6, p = s & 63;
                float va[8];
                float wa0 = wA0[j], wb0 = wB0[j], wa1 = wA1[j], wb1 = wB1[j];
                if (lidx0[j] >= 0) {
                    int l0 = lidx0[j], l1 = lidx1[j];
                    #pragma unroll
                    for (int ci = 0; ci < 8; ++ci) {
                        const float* bp = &XW[ci * 432];
                        float a0 = bp[l0], a1 = bp[l0 + 1];
                        float b0 = bp[l1], b1 = bp[l1 + 1];
                        va[ci] = wa0 * a0 + wb0 * a1 + wa1 * b0 + wb1 * b1;
                    }
                } else {
                    #pragma unroll
                    for (int ci = 0; ci < 8; ++ci) {
                        const char* pc = (const char*)(xb + (size_t)(h * 8 + ci) * HW);
                        f32x2 A  = *(const f32x2a*)(pc + moff[j][0]);
                        f32x2 Bv = *(const f32x2a*)(pc + moff[j][1]);
                        va[ci] = wa0 * A.x + wb0 * A.y + wa1 * Bv.x + wb1 * Bv.y;
                    }
                }
                short8 sv;
                #pragma unroll
                for (int ci = 0; ci < 8; ++ci) sv[ci] = (short)f2bf(va[ci]);
                *(short8*)&S[p * LDK + k * 16 + par * 8] = sv;
            }
        }
    };

    auto mfma_step = [&](int c) {
        #pragma unroll
        for (int ks = 0; ks < 5; ++ks) {
            short8 a[4];
            #pragma unroll
            for (int of = 0; of < 4; ++of) {
                int o = oh + of * 16 + row16;
                a[of] = *(const short8*)(wbf + o * WBF_COLS + c * 160 + ks * 32 + kq * 8);
            }
            #pragma unroll
            for (int pf = 0; pf < 2; ++pf) {
                int p = ph + pf * 16 + row16;
                short8 bfr = *(const short8*)&S[p * LDK + ks * 32 + kq * 8];
                #pragma unroll
                for (int of = 0; of < 4; ++of)
                    acc[of][pf] = __builtin_amdgcn_mfma_f32_16x16x32_bf16(
                        a[of], bfr, acc[of][pf], 0, 0, 0);
            }
        }
    };

    #pragma unroll 1
    for (int c = 0; c < 4; ++c) {
        regwrite();                         // XW <- half 2c
        regload(2 * c + 1);                 // next half in flight
        __syncthreads();
        sample_h(2 * c, 0);
        __syncthreads();                    // XW reads done
        regwrite();                         // XW <- half 2c+1
        if (c < 3) regload(2 * c + 2);
        __syncthreads();
        sample_h(2 * c + 1, 1);
        __syncthreads();                    // S complete for chunk c
        mfma_step(c);
    }

    // ---- store: C/D layout col(px)=lane&15, row(o)=(lane>>4)*4+r ----
    #pragma unroll
    for (int of = 0; of < 4; ++of) {
        #pragma unroll
        for (int r = 0; r < 4; ++r) {
            int o = oh + of * 16 + kq * 4 + r;
            float* orow = out + ((b * COUT + o) * H + ho) * W;
            #pragma unroll
            for (int pf = 0; pf < 2; ++pf) {
                int wo = wo0 + ph + pf * 16 + row16;
                orow[wo] = acc[of][pf][r];
            }
        }
    }
}

// ---------------------------------------------------------------------------
extern "C" void kernel_launch(void* const* d_in, const int* in_sizes, int n_in,
                              void* d_out, int out_size, void* d_ws, size_t ws_size,
                              hipStream_t stream)
{
    const float* x      = (const float*)d_in[0];
    const float* w_off  = (const float*)d_in[1];
    const float* b_off  = (const float*)d_in[2];
    const float* w_mask = (const float*)d_in[3];
    const float* b_mask = (const float*)d_in[4];
    const float* weight = (const float*)d_in[5];
    float* out   = (float*)d_out;

    float* bcat  = (float*)d_ws;
    short* wbf   = (short*)(bcat + 32);
    float* wconv = (float*)(wbf + WBF_SHORTS);

    prep_kernel<<<dim3((WCONV_SZ + 255) / 256), 256, 0, stream>>>(
        w_off, b_off, w_mask, b_mask, wconv, bcat);
    prep_wbf<<<dim3((WBF_SHORTS + 255) / 256), 256, 0, stream>>>(weight, wbf);
    fused_kernel<<<dim3(1024), 256, 0, stream>>>(x, wconv, bcat, wbf, out);
}

// Round 11
// 123.803 us; speedup vs baseline: 2.4872x; 2.4872x over previous
//
#include <hip/hip_runtime.h>
#include <math.h>

#define B 4
#define CIN 64
#define H 128
#define W 128
#define COUT 128
#define KK 9
#define HW (H*W)

#define OFFS_SZ (B*18*HW)
#define MASK_SZ (B*9*HW)
#define WTAP2_SZ (CIN*32*12)         // [c][f][12] (t-contiguous)
#define WBF_COLS 640                 // 4 chunks x 160 (144 real + 16 zero)
#define WBF_SHORTS (COUT*WBF_COLS)
#define LDK 168                      // LDS k-stride (shorts); 336B row stride

typedef __attribute__((ext_vector_type(8))) short short8;
typedef __attribute__((ext_vector_type(4))) float f32x4;
typedef __attribute__((ext_vector_type(2))) float f32x2;
typedef f32x2 __attribute__((aligned(4))) f32x2a;   // align-4 float2 load

// global->LDS DMA: 16B per lane, dest = wave-uniform base + lane*16.
#define GLDS16(g, l) __builtin_amdgcn_global_load_lds(                        \
    (__attribute__((address_space(1))) void*)(g),                             \
    (__attribute__((address_space(3))) void*)(l), 16, 0, 0)

__device__ __forceinline__ unsigned short f2bf(float f) {
    unsigned int u = __float_as_uint(f);
    u += 0x7fffu + ((u >> 16) & 1u);
    return (unsigned short)(u >> 16);
}

// ---------------------------------------------------------------------------
// prep: wtap2[c][f][12] (t-contiguous for b128 LDS reads), bcat biases.
// ---------------------------------------------------------------------------
__global__ void prep_kernel(const float* __restrict__ w_off, const float* __restrict__ b_off,
                            const float* __restrict__ w_mask, const float* __restrict__ b_mask,
                            float* __restrict__ wtap2, float* __restrict__ bcat)
{
    int idx = blockIdx.x * 256 + threadIdx.x;
    if (idx < WTAP2_SZ) {
        int t = idx % 12;
        int f = (idx / 12) & 31;
        int c = idx / 384;
        float v = 0.f;
        if (t < 9) {
            if (f < 18)      v = w_off[(f * CIN + c) * 9 + t];
            else if (f < 27) v = w_mask[((f - 18) * CIN + c) * 9 + t];
        }
        wtap2[idx] = v;
    }
    if (blockIdx.x == 0 && threadIdx.x < 32) {
        int f = threadIdx.x;
        float bv = 0.f;
        if (f < 18) bv = b_off[f];
        else if (f < 27) bv = b_mask[f - 18];
        bcat[f] = bv;
    }
}

// ---------------------------------------------------------------------------
// prep_wbf: einsum weights -> bf16, layout [o][cb*160 + tap*16 + ci];
// pad cols [144,160) per chunk are ZERO.
// ---------------------------------------------------------------------------
__global__ void prep_wbf(const float* __restrict__ wgt, short* __restrict__ wbf)
{
    int idx = blockIdx.x * 256 + threadIdx.x;
    if (idx >= WBF_SHORTS) return;
    int o  = idx / WBF_COLS;
    int kp = idx % WBF_COLS;
    int cb = kp / 160, r = kp % 160;
    float v = 0.f;
    if (r < 144) {
        int tap = r >> 4;
        int c   = cb * 16 + (r & 15);
        v = wgt[(o * CIN + c) * KK + tap];
    }
    wbf[idx] = (short)f2bf(v);
}

// ---------------------------------------------------------------------------
// XCD band swizzle (kept): T = (bid%8)*(n/8)+bid/8. No chunk stagger.
// ---------------------------------------------------------------------------

// ---------------------------------------------------------------------------
// offmask5 (FROZEN, ~48us measured R9): LDS-staged x + weights, async
// reg-staged next-chunk loads, channel unroll 2.
// ---------------------------------------------------------------------------
#define CC 8
__global__ __launch_bounds__(256)
__attribute__((amdgpu_waves_per_eu(4, 4)))
void offmask5_kernel(
    const float* __restrict__ x, const float* __restrict__ wtap2,
    const float* __restrict__ bcat, float* __restrict__ offs,
    float* __restrict__ mask)
{
    const int bid = blockIdx.x;
    const int T = (bid & 7) * 128 + (bid >> 3);
    const int wo0 = (T & 1) * 64;
    const int ho  = (T >> 1) & 127;
    const int b   = T >> 8;
    const int tid = threadIdx.x;
    const int f   = tid & 31;
    const int pg  = tid >> 5;
    const int px0 = pg * 8;

    __shared__ float lx[CC * 3 * 72];     // 6,912 B (base x = wo0-1)
    __shared__ float lw2[CC * 32 * 12];   // 12,288 B

    float acc[8];
    #pragma unroll
    for (int i = 0; i < 8; ++i) acc[i] = 0.f;

    const float* xb = x + b * CIN * HW;

    float nx[7], nw[12];
    auto load_chunk = [&](int cb) {
        #pragma unroll
        for (int i = 0; i < 7; ++i) {
            int idx = tid + i * 256;
            float v = 0.f;
            if (idx < CC * 3 * 72) {
                int c  = idx / 216;
                int rem = idx % 216;
                int ry = rem / 72;
                int j  = rem % 72;
                int g  = wo0 - 1 + j;
                int y  = ho - 1 + ry;
                if (y >= 0 && y < H && g >= 0 && g < W)
                    v = xb[(cb + c) * HW + y * W + g];
            }
            nx[i] = v;
        }
        #pragma unroll
        for (int i = 0; i < 12; ++i)
            nw[i] = wtap2[cb * (32 * 12) + tid + i * 256];
    };
    auto store_chunk = [&]() {
        #pragma unroll
        for (int i = 0; i < 7; ++i) {
            int idx = tid + i * 256;
            if (idx < CC * 3 * 72) lx[idx] = nx[i];
        }
        #pragma unroll
        for (int i = 0; i < 12; ++i)
            lw2[tid + i * 256] = nw[i];
    };

    load_chunk(0);
    store_chunk();
    __syncthreads();

    for (int cb = 0; cb < CIN; cb += CC) {
        bool more = (cb + CC) < CIN;
        if (more) load_chunk(cb + CC);   // in-flight during compute below

        #pragma unroll 2
        for (int c = 0; c < CC; ++c) {
            const float* wrow = &lw2[(c * 32 + f) * 12];
            f32x4 wq0 = *(const f32x4*)wrow;
            f32x4 wq1 = *(const f32x4*)(wrow + 4);
            float wv[9] = {wq0.x, wq0.y, wq0.z, wq0.w,
                           wq1.x, wq1.y, wq1.z, wq1.w, wrow[8]};
            float xr[3][10];
            #pragma unroll
            for (int q = 0; q < 3; ++q) {
                const float* xrow = &lx[(c * 3 + q) * 72 + px0];
                f32x4 xa = *(const f32x4*)xrow;
                f32x4 xb4 = *(const f32x4*)(xrow + 4);
                f32x2 xc = *(const f32x2*)(xrow + 8);
                xr[q][0] = xa.x;  xr[q][1] = xa.y;  xr[q][2] = xa.z;  xr[q][3] = xa.w;
                xr[q][4] = xb4.x; xr[q][5] = xb4.y; xr[q][6] = xb4.z; xr[q][7] = xb4.w;
                xr[q][8] = xc.x;  xr[q][9] = xc.y;
            }
            #pragma unroll
            for (int ky = 0; ky < 3; ++ky) {
                #pragma unroll
                for (int kx = 0; kx < 3; ++kx) {
                    float w = wv[ky * 3 + kx];
                    #pragma unroll
                    for (int p = 0; p < 8; ++p)
                        acc[p] += xr[ky][p + kx] * w;
                }
            }
        }

        if (more) {
            __syncthreads();     // all reads of lx/lw2 done
            store_chunk();
            __syncthreads();
        }
    }

    const float bv = bcat[f];
    if (f < 18) {
        float* op = offs + ((b * 18 + f) * H + ho) * W + wo0 + px0;
        #pragma unroll
        for (int p = 0; p < 8; ++p) op[p] = acc[p] + bv;
    } else if (f < 27) {
        float* mp = mask + ((b * 9 + (f - 18)) * H + ho) * W + wo0 + px0;
        #pragma unroll
        for (int p = 0; p < 8; ++p) {
            float a = acc[p] + bv;
            mp[p] = 1.f / (1.f + expf(-a));
        }
    }
}

// ---------------------------------------------------------------------------
// deform7 = deform4 (R5, 77us measured) with staging converted to
// global_load_lds DMA (no VGPR round-trip, no rg[] pressure).
// Correctness notes:
//  - XW slot idx writes bytes [idx*16, idx*16+16) -> lane-linear, matching
//    the DMA's wave-uniform-base + lane*16 semantics.
//  - boundary slots (g0=-4 / g0=128) get CLAMPED addresses -> garbage data,
//    but those columns are provably never read by the fast path
//    (wo0=0 => vvv>=4; wo0=64 => reads <=67 < 68) and slow path reads
//    global directly. Output bit-identical to R5's zero-fill.
// LDS 35,328 B -> 4 blocks/CU.
// ---------------------------------------------------------------------------
__global__ __launch_bounds__(256, 4) void deform7_kernel(
    const float* __restrict__ x, const float* __restrict__ offs,
    const float* __restrict__ maskp, const short* __restrict__ wbf,
    float* __restrict__ out)
{
    const int bid = blockIdx.x;
    const int T = (bid & 7) * 128 + (bid >> 3);
    const int wo0 = (T & 1) * 64;
    const int ho  = (T >> 1) & 127;
    const int b   = T >> 8;
    const int tid  = threadIdx.x;
    const int lane = tid & 63;
    const int wv   = tid >> 6;
    const int oh   = (wv & 1) * 64;
    const int ph   = (wv >> 1) * 32;
    const int row16 = lane & 15, kq = lane >> 4;

    __shared__ __align__(16) float XW[8 * 6 * 72];    // 13,824 B
    __shared__ __align__(16) short S[64 * LDK];       // 21,504 B

    if (tid < 128) {                      // zero K-pad [144,160) once
        short8 z = {0,0,0,0,0,0,0,0};
        *(short8*)&S[(tid >> 1) * LDK + 144 + (tid & 1) * 8] = z;
    }

    const float* xb = x + (size_t)b * CIN * HW;

    // ---- staging slots: slot idx -> XW float-index idx*4 (lane-linear),
    //      global offset with CLAMPED g0 (boundary slots never read).
    int st_goff[4];
    #pragma unroll
    for (int t = 0; t < 4; ++t) {
        int idx = tid + t * 256;
        int ci = idx / 108, rem = idx % 108, row = rem / 18, q = rem % 18;
        int ys = min(max(ho - 2 + row, 0), H - 1);
        int g0 = wo0 - 4 + q * 4;
        int g0c = min(max(g0, 0), W - 4);
        st_goff[t] = ci * HW + ys * W + g0c;
    }
    auto stage = [&](int h) {
        const float* base = xb + (size_t)h * 8 * HW;
        #pragma unroll
        for (int t = 0; t < 4; ++t) {
            if (tid + t * 256 < 864) {
                GLDS16(base + st_goff[t], &XW[(tid + t * 256) * 4]);
            }
        }
    };

    // ---- metadata: slot s = tid + j*256 -> (tap k = s>>6, px p = s&63) ----
    int   moff[3][2];
    int   lidx0[3], lidx1[3];
    float wA0[3], wB0[3], wA1[3], wB1[3];
    #pragma unroll
    for (int j = 0; j < 3; ++j) {
        moff[j][0] = 0; moff[j][1] = 0;
        lidx0[j] = -1; lidx1[j] = 0;
        wA0[j] = 0.f; wB0[j] = 0.f; wA1[j] = 0.f; wB1[j] = 0.f;
        int s = tid + j * 256;
        if (s < 576) {
            int k = s >> 6, p = s & 63;
            int wo = wo0 + p;
            int ky = k / 3, kx = k % 3;
            int obase = ((b * 18 + 2 * k) * H + ho) * W + wo;
            float dy = offs[obase];
            float dx = offs[obase + HW];
            float mk = maskp[((b * 9 + k) * H + ho) * W + wo];
            float py  = (float)(ho - 1 + ky) + dy;
            float pxf = (float)(wo - 1 + kx) + dx;
            float fy = floorf(py), fx = floorf(pxf);
            float ly = py - fy, lx = pxf - fx;
            int y0 = (int)fy, x0 = (int)fx;
            int y1 = y0 + 1,  x1 = x0 + 1;
            bool vy0 = (y0 >= 0) && (y0 < H);
            bool vy1 = (y1 >= 0) && (y1 < H);
            bool vx0 = (x0 >= 0) && (x0 < W);
            bool vx1 = (x1 >= 0) && (x1 < W);
            float w0 = (vy0 && vx0) ? (1.f - ly) * (1.f - lx) * mk : 0.f;
            float w1 = (vy0 && vx1) ? (1.f - ly) * lx * mk : 0.f;
            float w2 = (vy1 && vx0) ? ly * (1.f - lx) * mk : 0.f;
            float w3 = (vy1 && vx1) ? ly * lx * mk : 0.f;
            int lc = min(max(x0, 0), W - 2);
            bool sel = (x0 == lc);
            int r0 = min(max(y0, 0), H - 1);
            int r1 = min(max(y1, 0), H - 1);
            moff[j][0] = (r0 * W + lc) * 4;
            moff[j][1] = (r1 * W + lc) * 4;
            wA0[j] = sel ? w0 : w1;  wB0[j] = sel ? w1 : w0;
            wA1[j] = sel ? w2 : w3;  wB1[j] = sel ? w3 : w2;
            int u0 = r0 - (ho - 2);
            int u1 = r1 - (ho - 2);
            int vvv = lc - (wo0 - 4);
            bool fastp = ((unsigned)u0 < 6u) && ((unsigned)u1 < 6u)
                       && ((unsigned)vvv < 71u);
            lidx1[j] = u1 * 72 + vvv;
            lidx0[j] = fastp ? (u0 * 72 + vvv) : -1;
        }
    }

    f32x4 acc[4][2];
    #pragma unroll
    for (int i = 0; i < 4; ++i)
        #pragma unroll
        for (int j = 0; j < 2; ++j)
            acc[i][j] = (f32x4){0.f, 0.f, 0.f, 0.f};

    // ---- sample half h from XW (or global fallback), write ci-half of S ----
    auto sample = [&](int h) {
        #pragma unroll
        for (int j = 0; j < 3; ++j) {
            int s = tid + j * 256;
            if (s < 576) {
                int k = s >> 6, p = s & 63;
                float va[8];
                float wa0 = wA0[j], wb0 = wB0[j], wa1 = wA1[j], wb1 = wB1[j];
                if (lidx0[j] >= 0) {
                    int l0 = lidx0[j], l1 = lidx1[j];
                    #pragma unroll
                    for (int ci = 0; ci < 8; ++ci) {
                        const float* bp = &XW[ci * 432];
                        float a0 = bp[l0], a1 = bp[l0 + 1];
                        float b0 = bp[l1], b1 = bp[l1 + 1];
                        va[ci] = wa0 * a0 + wb0 * a1 + wa1 * b0 + wb1 * b1;
                    }
                } else {
                    #pragma unroll
                    for (int ci = 0; ci < 8; ++ci) {
                        const char* pc = (const char*)(xb + (size_t)(h * 8 + ci) * HW);
                        f32x2 A  = *(const f32x2a*)(pc + moff[j][0]);
                        f32x2 Bv = *(const f32x2a*)(pc + moff[j][1]);
                        va[ci] = wa0 * A.x + wb0 * A.y + wa1 * Bv.x + wb1 * Bv.y;
                    }
                }
                short8 sv;
                #pragma unroll
                for (int ci = 0; ci < 8; ++ci) sv[ci] = (short)f2bf(va[ci]);
                *(short8*)&S[p * LDK + k * 16 + (h & 1) * 8] = sv;
            }
        }
    };

    auto mfma_step = [&](int c) {
        #pragma unroll
        for (int ks = 0; ks < 5; ++ks) {
            short8 a[4];
            #pragma unroll
            for (int of = 0; of < 4; ++of) {
                int o = oh + of * 16 + row16;
                a[of] = *(const short8*)(wbf + o * WBF_COLS + c * 160 + ks * 32 + kq * 8);
            }
            #pragma unroll
            for (int pf = 0; pf < 2; ++pf) {
                int p = ph + pf * 16 + row16;
                short8 bfr = *(const short8*)&S[p * LDK + ks * 32 + kq * 8];
                #pragma unroll
                for (int of = 0; of < 4; ++of)
                    acc[of][pf] = __builtin_amdgcn_mfma_f32_16x16x32_bf16(
                        a[of], bfr, acc[of][pf], 0, 0, 0);
            }
        }
    };

    // ---- pipeline (R5 deform4 order): halves 0..7; mfma(c) under stage ----
    stage(0); __syncthreads(); sample(0); __syncthreads();
    stage(1); __syncthreads(); sample(1); __syncthreads();
    #pragma unroll 1
    for (int c = 0; c < 3; ++c) {
        stage(2 * c + 2);      // DMA in flight under MFMA below
        mfma_step(c);
        __syncthreads();
        sample(2 * c + 2);
        __syncthreads();
        stage(2 * c + 3);
        __syncthreads();
        sample(2 * c + 3);
        __syncthreads();
    }
    mfma_step(3);

    // ---- store: C/D layout col(px)=lane&15, row(o)=(lane>>4)*4+r ----
    #pragma unroll
    for (int of = 0; of < 4; ++of) {
        #pragma unroll
        for (int r = 0; r < 4; ++r) {
            int o = oh + of * 16 + kq * 4 + r;
            float* orow = out + ((b * COUT + o) * H + ho) * W;
            #pragma unroll
            for (int pf = 0; pf < 2; ++pf) {
                int wo = wo0 + ph + pf * 16 + row16;
                orow[wo] = acc[of][pf][r];
            }
        }
    }
}

// ---------------------------------------------------------------------------
extern "C" void kernel_launch(void* const* d_in, const int* in_sizes, int n_in,
                              void* d_out, int out_size, void* d_ws, size_t ws_size,
                              hipStream_t stream)
{
    const float* x      = (const float*)d_in[0];
    const float* w_off  = (const float*)d_in[1];
    const float* b_off  = (const float*)d_in[2];
    const float* w_mask = (const float*)d_in[3];
    const float* b_mask = (const float*)d_in[4];
    const float* weight = (const float*)d_in[5];
    float* out   = (float*)d_out;

    float* offs  = (float*)d_ws;
    float* maskb = offs + OFFS_SZ;
    float* bcat  = maskb + MASK_SZ;
    short* wbf   = (short*)(bcat + 32);
    float* wtap2 = bcat + 32 + WBF_SHORTS / 2;

    prep_kernel<<<dim3((WTAP2_SZ + 255) / 256), 256, 0, stream>>>(
        w_off, b_off, w_mask, b_mask, wtap2, bcat);
    prep_wbf<<<dim3((WBF_SHORTS + 255) / 256), 256, 0, stream>>>(weight, wbf);
    offmask5_kernel<<<dim3(1024), 256, 0, stream>>>(x, wtap2, bcat, offs, maskb);
    deform7_kernel<<<dim3(1024), 256, 0, stream>>>(x, offs, maskb, wbf, out);
}

// Round 12
// 116.144 us; speedup vs baseline: 2.6513x; 1.0659x over previous
//
#include <hip/hip_runtime.h>
#include <math.h>

#define B 4
#define CIN 64
#define H 128
#define W 128
#define COUT 128
#define KK 9
#define HW (H*W)

#define OFFS_SZ (B*18*HW)
#define MASK_SZ (B*9*HW)
#define WTAP2_SZ (CIN*32*12)         // [c][f][12] (t-contiguous)
#define WBF_COLS 640                 // 4 chunks x 160 (144 real + 16 zero)
#define WBF_SHORTS (COUT*WBF_COLS)
#define LDK 168                      // LDS k-stride (shorts); 336B row stride

typedef __attribute__((ext_vector_type(8))) short short8;
typedef __attribute__((ext_vector_type(4))) float f32x4;
typedef __attribute__((ext_vector_type(2))) float f32x2;
typedef f32x2 __attribute__((aligned(4))) f32x2a;   // align-4 float2 load

// global->LDS DMA: 16B per lane, dest = wave-uniform base + lane*16.
#define GLDS16(g, l) __builtin_amdgcn_global_load_lds(                        \
    (__attribute__((address_space(1))) void*)(g),                             \
    (__attribute__((address_space(3))) void*)(l), 16, 0, 0)

__device__ __forceinline__ unsigned short f2bf(float f) {
    unsigned int u = __float_as_uint(f);
    u += 0x7fffu + ((u >> 16) & 1u);
    return (unsigned short)(u >> 16);
}

// ---------------------------------------------------------------------------
// prep: wtap2[c][f][12] (t-contiguous for b128 LDS reads), bcat biases.
// ---------------------------------------------------------------------------
__global__ void prep_kernel(const float* __restrict__ w_off, const float* __restrict__ b_off,
                            const float* __restrict__ w_mask, const float* __restrict__ b_mask,
                            float* __restrict__ wtap2, float* __restrict__ bcat)
{
    int idx = blockIdx.x * 256 + threadIdx.x;
    if (idx < WTAP2_SZ) {
        int t = idx % 12;
        int f = (idx / 12) & 31;
        int c = idx / 384;
        float v = 0.f;
        if (t < 9) {
            if (f < 18)      v = w_off[(f * CIN + c) * 9 + t];
            else if (f < 27) v = w_mask[((f - 18) * CIN + c) * 9 + t];
        }
        wtap2[idx] = v;
    }
    if (blockIdx.x == 0 && threadIdx.x < 32) {
        int f = threadIdx.x;
        float bv = 0.f;
        if (f < 18) bv = b_off[f];
        else if (f < 27) bv = b_mask[f - 18];
        bcat[f] = bv;
    }
}

// ---------------------------------------------------------------------------
// prep_wbf: einsum weights -> bf16, layout [o][cb*160 + tap*16 + ci];
// pad cols [144,160) per chunk are ZERO.
// ---------------------------------------------------------------------------
__global__ void prep_wbf(const float* __restrict__ wgt, short* __restrict__ wbf)
{
    int idx = blockIdx.x * 256 + threadIdx.x;
    if (idx >= WBF_SHORTS) return;
    int o  = idx / WBF_COLS;
    int kp = idx % WBF_COLS;
    int cb = kp / 160, r = kp % 160;
    float v = 0.f;
    if (r < 144) {
        int tap = r >> 4;
        int c   = cb * 16 + (r & 15);
        v = wgt[(o * CIN + c) * KK + tap];
    }
    wbf[idx] = (short)f2bf(v);
}

// ---------------------------------------------------------------------------
// XCD band swizzle (kept): T = (bid%8)*(n/8)+bid/8. No chunk stagger.
// ---------------------------------------------------------------------------

// ---------------------------------------------------------------------------
// offmask5 (FROZEN, ~48us): LDS-staged x + weights, async reg-staged
// next-chunk loads, channel unroll 2.
// ---------------------------------------------------------------------------
#define CC 8
__global__ __launch_bounds__(256)
__attribute__((amdgpu_waves_per_eu(4, 4)))
void offmask5_kernel(
    const float* __restrict__ x, const float* __restrict__ wtap2,
    const float* __restrict__ bcat, float* __restrict__ offs,
    float* __restrict__ mask)
{
    const int bid = blockIdx.x;
    const int T = (bid & 7) * 128 + (bid >> 3);
    const int wo0 = (T & 1) * 64;
    const int ho  = (T >> 1) & 127;
    const int b   = T >> 8;
    const int tid = threadIdx.x;
    const int f   = tid & 31;
    const int pg  = tid >> 5;
    const int px0 = pg * 8;

    __shared__ float lx[CC * 3 * 72];     // 6,912 B (base x = wo0-1)
    __shared__ float lw2[CC * 32 * 12];   // 12,288 B

    float acc[8];
    #pragma unroll
    for (int i = 0; i < 8; ++i) acc[i] = 0.f;

    const float* xb = x + b * CIN * HW;

    float nx[7], nw[12];
    auto load_chunk = [&](int cb) {
        #pragma unroll
        for (int i = 0; i < 7; ++i) {
            int idx = tid + i * 256;
            float v = 0.f;
            if (idx < CC * 3 * 72) {
                int c  = idx / 216;
                int rem = idx % 216;
                int ry = rem / 72;
                int j  = rem % 72;
                int g  = wo0 - 1 + j;
                int y  = ho - 1 + ry;
                if (y >= 0 && y < H && g >= 0 && g < W)
                    v = xb[(cb + c) * HW + y * W + g];
            }
            nx[i] = v;
        }
        #pragma unroll
        for (int i = 0; i < 12; ++i)
            nw[i] = wtap2[cb * (32 * 12) + tid + i * 256];
    };
    auto store_chunk = [&]() {
        #pragma unroll
        for (int i = 0; i < 7; ++i) {
            int idx = tid + i * 256;
            if (idx < CC * 3 * 72) lx[idx] = nx[i];
        }
        #pragma unroll
        for (int i = 0; i < 12; ++i)
            lw2[tid + i * 256] = nw[i];
    };

    load_chunk(0);
    store_chunk();
    __syncthreads();

    for (int cb = 0; cb < CIN; cb += CC) {
        bool more = (cb + CC) < CIN;
        if (more) load_chunk(cb + CC);   // in-flight during compute below

        #pragma unroll 2
        for (int c = 0; c < CC; ++c) {
            const float* wrow = &lw2[(c * 32 + f) * 12];
            f32x4 wq0 = *(const f32x4*)wrow;
            f32x4 wq1 = *(const f32x4*)(wrow + 4);
            float wv[9] = {wq0.x, wq0.y, wq0.z, wq0.w,
                           wq1.x, wq1.y, wq1.z, wq1.w, wrow[8]};
            float xr[3][10];
            #pragma unroll
            for (int q = 0; q < 3; ++q) {
                const float* xrow = &lx[(c * 3 + q) * 72 + px0];
                f32x4 xa = *(const f32x4*)xrow;
                f32x4 xb4 = *(const f32x4*)(xrow + 4);
                f32x2 xc = *(const f32x2*)(xrow + 8);
                xr[q][0] = xa.x;  xr[q][1] = xa.y;  xr[q][2] = xa.z;  xr[q][3] = xa.w;
                xr[q][4] = xb4.x; xr[q][5] = xb4.y; xr[q][6] = xb4.z; xr[q][7] = xb4.w;
                xr[q][8] = xc.x;  xr[q][9] = xc.y;
            }
            #pragma unroll
            for (int ky = 0; ky < 3; ++ky) {
                #pragma unroll
                for (int kx = 0; kx < 3; ++kx) {
                    float w = wv[ky * 3 + kx];
                    #pragma unroll
                    for (int p = 0; p < 8; ++p)
                        acc[p] += xr[ky][p + kx] * w;
                }
            }
        }

        if (more) {
            __syncthreads();     // all reads of lx/lw2 done
            store_chunk();
            __syncthreads();
        }
    }

    const float bv = bcat[f];
    if (f < 18) {
        float* op = offs + ((b * 18 + f) * H + ho) * W + wo0 + px0;
        #pragma unroll
        for (int p = 0; p < 8; ++p) op[p] = acc[p] + bv;
    } else if (f < 27) {
        float* mp = mask + ((b * 9 + (f - 18)) * H + ho) * W + wo0 + px0;
        #pragma unroll
        for (int p = 0; p < 8; ++p) {
            float a = acc[p] + bv;
            mp[p] = 1.f / (1.f + expf(-a));
        }
    }
}

// ---------------------------------------------------------------------------
// deform8 = deform7 (70us, DMA staging) + two fixes:
//  1. bilinear LDS reads paired as f32x2 (ds_read2_b32): 576 -> 288
//     LDS wave-instrs/thread -- the dominant cost term.
//  2. __launch_bounds__(256,2): allocator's VGPR target tracks requested
//     min-occupancy (R4: bound 3->80 VGPR; R5: bound 4->64+spill). Bound 2
//     -> <=128 VGPR budget, metadata spill (28MB WRITE excess) gone.
//     Occupancy stays 4 blocks/CU: LDS (35,328B) binds, not VGPRs.
// ---------------------------------------------------------------------------
__global__ __launch_bounds__(256, 2) void deform8_kernel(
    const float* __restrict__ x, const float* __restrict__ offs,
    const float* __restrict__ maskp, const short* __restrict__ wbf,
    float* __restrict__ out)
{
    const int bid = blockIdx.x;
    const int T = (bid & 7) * 128 + (bid >> 3);
    const int wo0 = (T & 1) * 64;
    const int ho  = (T >> 1) & 127;
    const int b   = T >> 8;
    const int tid  = threadIdx.x;
    const int lane = tid & 63;
    const int wv   = tid >> 6;
    const int oh   = (wv & 1) * 64;
    const int ph   = (wv >> 1) * 32;
    const int row16 = lane & 15, kq = lane >> 4;

    __shared__ __align__(16) float XW[8 * 6 * 72];    // 13,824 B
    __shared__ __align__(16) short S[64 * LDK];       // 21,504 B

    if (tid < 128) {                      // zero K-pad [144,160) once
        short8 z = {0,0,0,0,0,0,0,0};
        *(short8*)&S[(tid >> 1) * LDK + 144 + (tid & 1) * 8] = z;
    }

    const float* xb = x + (size_t)b * CIN * HW;

    // ---- staging slots: slot idx -> XW float-index idx*4 (lane-linear),
    //      global offset with CLAMPED g0 (boundary slots never read).
    int st_goff[4];
    #pragma unroll
    for (int t = 0; t < 4; ++t) {
        int idx = tid + t * 256;
        int ci = idx / 108, rem = idx % 108, row = rem / 18, q = rem % 18;
        int ys = min(max(ho - 2 + row, 0), H - 1);
        int g0 = wo0 - 4 + q * 4;
        int g0c = min(max(g0, 0), W - 4);
        st_goff[t] = ci * HW + ys * W + g0c;
    }
    auto stage = [&](int h) {
        const float* base = xb + (size_t)h * 8 * HW;
        #pragma unroll
        for (int t = 0; t < 4; ++t) {
            if (tid + t * 256 < 864) {
                GLDS16(base + st_goff[t], &XW[(tid + t * 256) * 4]);
            }
        }
    };

    // ---- metadata: slot s = tid + j*256 -> (tap k = s>>6, px p = s&63) ----
    int   moff[3][2];
    int   lidx0[3], lidx1[3];
    float wA0[3], wB0[3], wA1[3], wB1[3];
    #pragma unroll
    for (int j = 0; j < 3; ++j) {
        moff[j][0] = 0; moff[j][1] = 0;
        lidx0[j] = -1; lidx1[j] = 0;
        wA0[j] = 0.f; wB0[j] = 0.f; wA1[j] = 0.f; wB1[j] = 0.f;
        int s = tid + j * 256;
        if (s < 576) {
            int k = s >> 6, p = s & 63;
            int wo = wo0 + p;
            int ky = k / 3, kx = k % 3;
            int obase = ((b * 18 + 2 * k) * H + ho) * W + wo;
            float dy = offs[obase];
            float dx = offs[obase + HW];
            float mk = maskp[((b * 9 + k) * H + ho) * W + wo];
            float py  = (float)(ho - 1 + ky) + dy;
            float pxf = (float)(wo - 1 + kx) + dx;
            float fy = floorf(py), fx = floorf(pxf);
            float ly = py - fy, lx = pxf - fx;
            int y0 = (int)fy, x0 = (int)fx;
            int y1 = y0 + 1,  x1 = x0 + 1;
            bool vy0 = (y0 >= 0) && (y0 < H);
            bool vy1 = (y1 >= 0) && (y1 < H);
            bool vx0 = (x0 >= 0) && (x0 < W);
            bool vx1 = (x1 >= 0) && (x1 < W);
            float w0 = (vy0 && vx0) ? (1.f - ly) * (1.f - lx) * mk : 0.f;
            float w1 = (vy0 && vx1) ? (1.f - ly) * lx * mk : 0.f;
            float w2 = (vy1 && vx0) ? ly * (1.f - lx) * mk : 0.f;
            float w3 = (vy1 && vx1) ? ly * lx * mk : 0.f;
            int lc = min(max(x0, 0), W - 2);
            bool sel = (x0 == lc);
            int r0 = min(max(y0, 0), H - 1);
            int r1 = min(max(y1, 0), H - 1);
            moff[j][0] = (r0 * W + lc) * 4;
            moff[j][1] = (r1 * W + lc) * 4;
            wA0[j] = sel ? w0 : w1;  wB0[j] = sel ? w1 : w0;
            wA1[j] = sel ? w2 : w3;  wB1[j] = sel ? w3 : w2;
            int u0 = r0 - (ho - 2);
            int u1 = r1 - (ho - 2);
            int vvv = lc - (wo0 - 4);
            bool fastp = ((unsigned)u0 < 6u) && ((unsigned)u1 < 6u)
                       && ((unsigned)vvv < 71u);
            lidx1[j] = u1 * 72 + vvv;
            lidx0[j] = fastp ? (u0 * 72 + vvv) : -1;
        }
    }

    f32x4 acc[4][2];
    #pragma unroll
    for (int i = 0; i < 4; ++i)
        #pragma unroll
        for (int j = 0; j < 2; ++j)
            acc[i][j] = (f32x4){0.f, 0.f, 0.f, 0.f};

    // ---- sample half h from XW (paired f32x2 LDS reads) or global ----
    auto sample = [&](int h) {
        #pragma unroll
        for (int j = 0; j < 3; ++j) {
            int s = tid + j * 256;
            if (s < 576) {
                int k = s >> 6, p = s & 63;
                float va[8];
                float wa0 = wA0[j], wb0 = wB0[j], wa1 = wA1[j], wb1 = wB1[j];
                if (lidx0[j] >= 0) {
                    int l0 = lidx0[j], l1 = lidx1[j];
                    #pragma unroll
                    for (int ci = 0; ci < 8; ++ci) {
                        const float* bp = &XW[ci * 432];
                        f32x2 A  = *(const f32x2a*)(bp + l0);   // ds_read2_b32
                        f32x2 Bv = *(const f32x2a*)(bp + l1);
                        va[ci] = wa0 * A.x + wb0 * A.y + wa1 * Bv.x + wb1 * Bv.y;
                    }
                } else {
                    #pragma unroll
                    for (int ci = 0; ci < 8; ++ci) {
                        const char* pc = (const char*)(xb + (size_t)(h * 8 + ci) * HW);
                        f32x2 A  = *(const f32x2a*)(pc + moff[j][0]);
                        f32x2 Bv = *(const f32x2a*)(pc + moff[j][1]);
                        va[ci] = wa0 * A.x + wb0 * A.y + wa1 * Bv.x + wb1 * Bv.y;
                    }
                }
                short8 sv;
                #pragma unroll
                for (int ci = 0; ci < 8; ++ci) sv[ci] = (short)f2bf(va[ci]);
                *(short8*)&S[p * LDK + k * 16 + (h & 1) * 8] = sv;
            }
        }
    };

    auto mfma_step = [&](int c) {
        #pragma unroll
        for (int ks = 0; ks < 5; ++ks) {
            short8 a[4];
            #pragma unroll
            for (int of = 0; of < 4; ++of) {
                int o = oh + of * 16 + row16;
                a[of] = *(const short8*)(wbf + o * WBF_COLS + c * 160 + ks * 32 + kq * 8);
            }
            #pragma unroll
            for (int pf = 0; pf < 2; ++pf) {
                int p = ph + pf * 16 + row16;
                short8 bfr = *(const short8*)&S[p * LDK + ks * 32 + kq * 8];
                #pragma unroll
                for (int of = 0; of < 4; ++of)
                    acc[of][pf] = __builtin_amdgcn_mfma_f32_16x16x32_bf16(
                        a[of], bfr, acc[of][pf], 0, 0, 0);
            }
        }
    };

    // ---- pipeline: halves 0..7; mfma(c) under DMA stage ----
    stage(0); __syncthreads(); sample(0); __syncthreads();
    stage(1); __syncthreads(); sample(1); __syncthreads();
    #pragma unroll 1
    for (int c = 0; c < 3; ++c) {
        stage(2 * c + 2);      // DMA in flight under MFMA below
        mfma_step(c);
        __syncthreads();
        sample(2 * c + 2);
        __syncthreads();
        stage(2 * c + 3);
        __syncthreads();
        sample(2 * c + 3);
        __syncthreads();
    }
    mfma_step(3);

    // ---- store: C/D layout col(px)=lane&15, row(o)=(lane>>4)*4+r ----
    #pragma unroll
    for (int of = 0; of < 4; ++of) {
        #pragma unroll
        for (int r = 0; r < 4; ++r) {
            int o = oh + of * 16 + kq * 4 + r;
            float* orow = out + ((b * COUT + o) * H + ho) * W;
            #pragma unroll
            for (int pf = 0; pf < 2; ++pf) {
                int wo = wo0 + ph + pf * 16 + row16;
                orow[wo] = acc[of][pf][r];
            }
        }
    }
}

// ---------------------------------------------------------------------------
extern "C" void kernel_launch(void* const* d_in, const int* in_sizes, int n_in,
                              void* d_out, int out_size, void* d_ws, size_t ws_size,
                              hipStream_t stream)
{
    const float* x      = (const float*)d_in[0];
    const float* w_off  = (const float*)d_in[1];
    const float* b_off  = (const float*)d_in[2];
    const float* w_mask = (const float*)d_in[3];
    const float* b_mask = (const float*)d_in[4];
    const float* weight = (const float*)d_in[5];
    float* out   = (float*)d_out;

    float* offs  = (float*)d_ws;
    float* maskb = offs + OFFS_SZ;
    float* bcat  = maskb + MASK_SZ;
    short* wbf   = (short*)(bcat + 32);
    float* wtap2 = bcat + 32 + WBF_SHORTS / 2;

    prep_kernel<<<dim3((WTAP2_SZ + 255) / 256), 256, 0, stream>>>(
        w_off, b_off, w_mask, b_mask, wtap2, bcat);
    prep_wbf<<<dim3((WBF_SHORTS + 255) / 256), 256, 0, stream>>>(weight, wbf);
    offmask5_kernel<<<dim3(1024), 256, 0, stream>>>(x, wtap2, bcat, offs, maskb);
    deform8_kernel<<<dim3(1024), 256, 0, stream>>>(x, offs, maskb, wbf, out);
}

// Round 13
// 90.948 us; speedup vs baseline: 3.3857x; 1.2770x over previous
//
#include <hip/hip_runtime.h>
#include <math.h>

#define B 4
#define CIN 64
#define H 128
#define W 128
#define COUT 128
#define KK 9
#define HW (H*W)

#define OFFS_SZ (B*18*HW)
#define MASK_SZ (B*9*HW)
#define WBF_COLS 640                 // 4 chunks x 160 (144 real + 16 zero)
#define WBF_SHORTS (COUT*WBF_COLS)
#define WCV_SHORTS (32*640)          // offmask conv weights, bf16, K-padded
#define LDK 168                      // LDS k-stride (shorts); 336B row stride

typedef __attribute__((ext_vector_type(8))) short short8;
typedef __attribute__((ext_vector_type(4))) float f32x4;
typedef __attribute__((ext_vector_type(2))) float f32x2;
typedef f32x2 __attribute__((aligned(4))) f32x2a;   // align-4 float2 load

// global->LDS DMA: 16B per lane, dest = wave-uniform base + lane*16.
#define GLDS16(g, l) __builtin_amdgcn_global_load_lds(                        \
    (__attribute__((address_space(1))) void*)(g),                             \
    (__attribute__((address_space(3))) void*)(l), 16, 0, 0)

__device__ __forceinline__ unsigned short f2bf(float f) {
    unsigned int u = __float_as_uint(f);
    u += 0x7fffu + ((u >> 16) & 1u);
    return (unsigned short)(u >> 16);
}

// ---------------------------------------------------------------------------
// prep_wcv: offmask conv weights -> bf16 wcv[f(32)][cb*160 + tap*16 + ci]
// (identical K-160-padded layout to wbf; rows 27..31 and cols [144,160) = 0).
// Also fills bcat (32 biases).
// ---------------------------------------------------------------------------
__global__ void prep_wcv(const float* __restrict__ w_off, const float* __restrict__ b_off,
                         const float* __restrict__ w_mask, const float* __restrict__ b_mask,
                         short* __restrict__ wcv, float* __restrict__ bcat)
{
    int idx = blockIdx.x * 256 + threadIdx.x;
    if (idx < WCV_SHORTS) {
        int f  = idx / 640;
        int kp = idx % 640;
        int cb = kp / 160, r = kp % 160;
        float v = 0.f;
        if (r < 144) {
            int tap = r >> 4;
            int c   = cb * 16 + (r & 15);
            if (f < 18)      v = w_off[(f * CIN + c) * 9 + tap];
            else if (f < 27) v = w_mask[((f - 18) * CIN + c) * 9 + tap];
        }
        wcv[idx] = (short)f2bf(v);
    }
    if (blockIdx.x == 0 && threadIdx.x < 32) {
        int f = threadIdx.x;
        float bv = 0.f;
        if (f < 18) bv = b_off[f];
        else if (f < 27) bv = b_mask[f - 18];
        bcat[f] = bv;
    }
}

// ---------------------------------------------------------------------------
// prep_wbf: einsum weights -> bf16, layout [o][cb*160 + tap*16 + ci];
// pad cols [144,160) per chunk are ZERO.
// ---------------------------------------------------------------------------
__global__ void prep_wbf(const float* __restrict__ wgt, short* __restrict__ wbf)
{
    int idx = blockIdx.x * 256 + threadIdx.x;
    if (idx >= WBF_SHORTS) return;
    int o  = idx / WBF_COLS;
    int kp = idx % WBF_COLS;
    int cb = kp / 160, r = kp % 160;
    float v = 0.f;
    if (r < 144) {
        int tap = r >> 4;
        int c   = cb * 16 + (r & 15);
        v = wgt[(o * CIN + c) * KK + tap];
    }
    wbf[idx] = (short)f2bf(v);
}

// ---------------------------------------------------------------------------
// XCD band swizzle (kept): T = (bid%8)*(n/8)+bid/8. No chunk stagger.
// ---------------------------------------------------------------------------

// ---------------------------------------------------------------------------
// offmask6: MFMA version of the 27-filter conv (R12: offmask5 was
// VALU-bound at 67%, 4608 scalar FMA/thread). M=32(27) x N=64px x K=576:
//  - 3-row x 72-col window staged via global_load_lds (deform8 idiom);
//  - im2col built in LDS S2[px][tap*16+ci] bf16 (~300 VALU/thread);
//  - 10 MFMA/wave/chunk, weights wcv (same padded-K layout as wbf);
//  - zero-padding handled in build (garbage clamp columns never read).
// LDS: XW3 6,912 + S2 21,504 = 28,416 B -> 4+ blocks/CU.
// ---------------------------------------------------------------------------
__global__ __launch_bounds__(256, 2) void offmask6_kernel(
    const float* __restrict__ x, const short* __restrict__ wcv,
    const float* __restrict__ bcat, float* __restrict__ offs,
    float* __restrict__ mask)
{
    const int bid = blockIdx.x;
    const int T = (bid & 7) * 128 + (bid >> 3);
    const int wo0 = (T & 1) * 64;
    const int ho  = (T >> 1) & 127;
    const int b   = T >> 8;
    const int tid  = threadIdx.x;
    const int lane = tid & 63;
    const int wv   = tid >> 6;
    const int row16 = lane & 15, kq = lane >> 4;

    __shared__ __align__(16) float XW3[8 * 3 * 72];   // 6,912 B
    __shared__ __align__(16) short S2[64 * LDK];      // 21,504 B

    if (tid < 128) {                      // zero K-pad [144,160) once
        short8 z = {0,0,0,0,0,0,0,0};
        *(short8*)&S2[(tid >> 1) * LDK + 144 + (tid & 1) * 8] = z;
    }

    const float* xb = x + (size_t)b * CIN * HW;

    // ---- staging slots: 432 = 8ch x 3row x 18quad, lane-linear dest ----
    int st_goff[2];
    #pragma unroll
    for (int t = 0; t < 2; ++t) {
        int idx = tid + t * 256;
        int ci = idx / 54, rem = idx % 54, row = rem / 18, q = rem % 18;
        int ys = min(max(ho - 1 + row, 0), H - 1);
        int g0 = wo0 - 4 + q * 4;
        int g0c = min(max(g0, 0), W - 4);
        st_goff[t] = ci * HW + ys * W + g0c;
    }
    auto stage = [&](int h) {
        const float* base = xb + (size_t)h * 8 * HW;
        #pragma unroll
        for (int t = 0; t < 2; ++t) {
            if (tid + t * 256 < 432) {
                GLDS16(base + st_goff[t], &XW3[(tid + t * 256) * 4]);
            }
        }
    };

    // ---- im2col slot metadata: s = tid+j*256 -> (tap k, px p) ----
    int bidx[3];                           // XW3 col-row offset; -1 = zero
    #pragma unroll
    for (int j = 0; j < 3; ++j) {
        bidx[j] = -1;
        int s = tid + j * 256;
        if (s < 576) {
            int k = s >> 6, p = s & 63;
            int ky = k / 3, kx = k % 3;
            bool ok = ((unsigned)(ho - 1 + ky) < (unsigned)H)
                   && ((unsigned)(wo0 + p - 1 + kx) < (unsigned)W);
            if (ok) bidx[j] = ky * 72 + (p + 3 + kx);
        }
    }

    f32x4 acc2[2];
    acc2[0] = (f32x4){0.f, 0.f, 0.f, 0.f};
    acc2[1] = (f32x4){0.f, 0.f, 0.f, 0.f};

    // ---- build im2col half h into S2 ----
    auto build = [&](int h) {
        #pragma unroll
        for (int j = 0; j < 3; ++j) {
            int s = tid + j * 256;
            if (s < 576) {
                int k = s >> 6, p = s & 63;
                short8 sv = {0,0,0,0,0,0,0,0};
                if (bidx[j] >= 0) {
                    #pragma unroll
                    for (int ci = 0; ci < 8; ++ci)
                        sv[ci] = (short)f2bf(XW3[ci * 216 + bidx[j]]);
                }
                *(short8*)&S2[p * LDK + k * 16 + (h & 1) * 8] = sv;
            }
        }
    };

    // ---- MFMA over chunk c: wave wv owns px tile [wv*16, wv*16+16) ----
    auto mfma_off = [&](int c) {
        #pragma unroll
        for (int ks = 0; ks < 5; ++ks) {
            short8 a0 = *(const short8*)(wcv + (row16)      * 640 + c * 160 + ks * 32 + kq * 8);
            short8 a1 = *(const short8*)(wcv + (16 + row16) * 640 + c * 160 + ks * 32 + kq * 8);
            short8 bfr = *(const short8*)&S2[(wv * 16 + row16) * LDK + ks * 32 + kq * 8];
            acc2[0] = __builtin_amdgcn_mfma_f32_16x16x32_bf16(a0, bfr, acc2[0], 0, 0, 0);
            acc2[1] = __builtin_amdgcn_mfma_f32_16x16x32_bf16(a1, bfr, acc2[1], 0, 0, 0);
        }
    };

    // ---- pipeline (deform8 shape): DMA(h+1) in flight under build/MFMA ----
    stage(0); __syncthreads(); build(0); __syncthreads();
    stage(1); __syncthreads(); build(1); __syncthreads();
    #pragma unroll 1
    for (int c = 0; c < 3; ++c) {
        stage(2 * c + 2);
        mfma_off(c);
        __syncthreads();
        build(2 * c + 2);
        __syncthreads();
        stage(2 * c + 3);
        __syncthreads();
        build(2 * c + 3);
        __syncthreads();
    }
    mfma_off(3);

    // ---- store: row(f) = of*16 + kq*4 + r, col(px) = wv*16 + row16 ----
    const int px = wo0 + wv * 16 + row16;
    #pragma unroll
    for (int of = 0; of < 2; ++of) {
        #pragma unroll
        for (int r = 0; r < 4; ++r) {
            int f = of * 16 + kq * 4 + r;
            if (f < 27) {
                float v = acc2[of][r] + bcat[f];
                if (f < 18) {
                    offs[((b * 18 + f) * H + ho) * W + px] = v;
                } else {
                    mask[((b * 9 + (f - 18)) * H + ho) * W + px] =
                        1.f / (1.f + expf(-v));
                }
            }
        }
    }
}

// ---------------------------------------------------------------------------
// deform8 (FROZEN, ~48us): DMA staging + paired f32x2 LDS bilinear reads +
// __launch_bounds__(256,2) (allocator targets <=128 VGPR, no spill).
// ---------------------------------------------------------------------------
__global__ __launch_bounds__(256, 2) void deform8_kernel(
    const float* __restrict__ x, const float* __restrict__ offs,
    const float* __restrict__ maskp, const short* __restrict__ wbf,
    float* __restrict__ out)
{
    const int bid = blockIdx.x;
    const int T = (bid & 7) * 128 + (bid >> 3);
    const int wo0 = (T & 1) * 64;
    const int ho  = (T >> 1) & 127;
    const int b   = T >> 8;
    const int tid  = threadIdx.x;
    const int lane = tid & 63;
    const int wv   = tid >> 6;
    const int oh   = (wv & 1) * 64;
    const int ph   = (wv >> 1) * 32;
    const int row16 = lane & 15, kq = lane >> 4;

    __shared__ __align__(16) float XW[8 * 6 * 72];    // 13,824 B
    __shared__ __align__(16) short S[64 * LDK];       // 21,504 B

    if (tid < 128) {                      // zero K-pad [144,160) once
        short8 z = {0,0,0,0,0,0,0,0};
        *(short8*)&S[(tid >> 1) * LDK + 144 + (tid & 1) * 8] = z;
    }

    const float* xb = x + (size_t)b * CIN * HW;

    int st_goff[4];
    #pragma unroll
    for (int t = 0; t < 4; ++t) {
        int idx = tid + t * 256;
        int ci = idx / 108, rem = idx % 108, row = rem / 18, q = rem % 18;
        int ys = min(max(ho - 2 + row, 0), H - 1);
        int g0 = wo0 - 4 + q * 4;
        int g0c = min(max(g0, 0), W - 4);
        st_goff[t] = ci * HW + ys * W + g0c;
    }
    auto stage = [&](int h) {
        const float* base = xb + (size_t)h * 8 * HW;
        #pragma unroll
        for (int t = 0; t < 4; ++t) {
            if (tid + t * 256 < 864) {
                GLDS16(base + st_goff[t], &XW[(tid + t * 256) * 4]);
            }
        }
    };

    int   moff[3][2];
    int   lidx0[3], lidx1[3];
    float wA0[3], wB0[3], wA1[3], wB1[3];
    #pragma unroll
    for (int j = 0; j < 3; ++j) {
        moff[j][0] = 0; moff[j][1] = 0;
        lidx0[j] = -1; lidx1[j] = 0;
        wA0[j] = 0.f; wB0[j] = 0.f; wA1[j] = 0.f; wB1[j] = 0.f;
        int s = tid + j * 256;
        if (s < 576) {
            int k = s >> 6, p = s & 63;
            int wo = wo0 + p;
            int ky = k / 3, kx = k % 3;
            int obase = ((b * 18 + 2 * k) * H + ho) * W + wo;
            float dy = offs[obase];
            float dx = offs[obase + HW];
            float mk = maskp[((b * 9 + k) * H + ho) * W + wo];
            float py  = (float)(ho - 1 + ky) + dy;
            float pxf = (float)(wo - 1 + kx) + dx;
            float fy = floorf(py), fx = floorf(pxf);
            float ly = py - fy, lx = pxf - fx;
            int y0 = (int)fy, x0 = (int)fx;
            int y1 = y0 + 1,  x1 = x0 + 1;
            bool vy0 = (y0 >= 0) && (y0 < H);
            bool vy1 = (y1 >= 0) && (y1 < H);
            bool vx0 = (x0 >= 0) && (x0 < W);
            bool vx1 = (x1 >= 0) && (x1 < W);
            float w0 = (vy0 && vx0) ? (1.f - ly) * (1.f - lx) * mk : 0.f;
            float w1 = (vy0 && vx1) ? (1.f - ly) * lx * mk : 0.f;
            float w2 = (vy1 && vx0) ? ly * (1.f - lx) * mk : 0.f;
            float w3 = (vy1 && vx1) ? ly * lx * mk : 0.f;
            int lc = min(max(x0, 0), W - 2);
            bool sel = (x0 == lc);
            int r0 = min(max(y0, 0), H - 1);
            int r1 = min(max(y1, 0), H - 1);
            moff[j][0] = (r0 * W + lc) * 4;
            moff[j][1] = (r1 * W + lc) * 4;
            wA0[j] = sel ? w0 : w1;  wB0[j] = sel ? w1 : w0;
            wA1[j] = sel ? w2 : w3;  wB1[j] = sel ? w3 : w2;
            int u0 = r0 - (ho - 2);
            int u1 = r1 - (ho - 2);
            int vvv = lc - (wo0 - 4);
            bool fastp = ((unsigned)u0 < 6u) && ((unsigned)u1 < 6u)
                       && ((unsigned)vvv < 71u);
            lidx1[j] = u1 * 72 + vvv;
            lidx0[j] = fastp ? (u0 * 72 + vvv) : -1;
        }
    }

    f32x4 acc[4][2];
    #pragma unroll
    for (int i = 0; i < 4; ++i)
        #pragma unroll
        for (int j = 0; j < 2; ++j)
            acc[i][j] = (f32x4){0.f, 0.f, 0.f, 0.f};

    auto sample = [&](int h) {
        #pragma unroll
        for (int j = 0; j < 3; ++j) {
            int s = tid + j * 256;
            if (s < 576) {
                int k = s >> 6, p = s & 63;
                float va[8];
                float wa0 = wA0[j], wb0 = wB0[j], wa1 = wA1[j], wb1 = wB1[j];
                if (lidx0[j] >= 0) {
                    int l0 = lidx0[j], l1 = lidx1[j];
                    #pragma unroll
                    for (int ci = 0; ci < 8; ++ci) {
                        const float* bp = &XW[ci * 432];
                        f32x2 A  = *(const f32x2a*)(bp + l0);   // ds_read2_b32
                        f32x2 Bv = *(const f32x2a*)(bp + l1);
                        va[ci] = wa0 * A.x + wb0 * A.y + wa1 * Bv.x + wb1 * Bv.y;
                    }
                } else {
                    #pragma unroll
                    for (int ci = 0; ci < 8; ++ci) {
                        const char* pc = (const char*)(xb + (size_t)(h * 8 + ci) * HW);
                        f32x2 A  = *(const f32x2a*)(pc + moff[j][0]);
                        f32x2 Bv = *(const f32x2a*)(pc + moff[j][1]);
                        va[ci] = wa0 * A.x + wb0 * A.y + wa1 * Bv.x + wb1 * Bv.y;
                    }
                }
                short8 sv;
                #pragma unroll
                for (int ci = 0; ci < 8; ++ci) sv[ci] = (short)f2bf(va[ci]);
                *(short8*)&S[p * LDK + k * 16 + (h & 1) * 8] = sv;
            }
        }
    };

    auto mfma_step = [&](int c) {
        #pragma unroll
        for (int ks = 0; ks < 5; ++ks) {
            short8 a[4];
            #pragma unroll
            for (int of = 0; of < 4; ++of) {
                int o = oh + of * 16 + row16;
                a[of] = *(const short8*)(wbf + o * WBF_COLS + c * 160 + ks * 32 + kq * 8);
            }
            #pragma unroll
            for (int pf = 0; pf < 2; ++pf) {
                int p = ph + pf * 16 + row16;
                short8 bfr = *(const short8*)&S[p * LDK + ks * 32 + kq * 8];
                #pragma unroll
                for (int of = 0; of < 4; ++of)
                    acc[of][pf] = __builtin_amdgcn_mfma_f32_16x16x32_bf16(
                        a[of], bfr, acc[of][pf], 0, 0, 0);
            }
        }
    };

    stage(0); __syncthreads(); sample(0); __syncthreads();
    stage(1); __syncthreads(); sample(1); __syncthreads();
    #pragma unroll 1
    for (int c = 0; c < 3; ++c) {
        stage(2 * c + 2);      // DMA in flight under MFMA below
        mfma_step(c);
        __syncthreads();
        sample(2 * c + 2);
        __syncthreads();
        stage(2 * c + 3);
        __syncthreads();
        sample(2 * c + 3);
        __syncthreads();
    }
    mfma_step(3);

    #pragma unroll
    for (int of = 0; of < 4; ++of) {
        #pragma unroll
        for (int r = 0; r < 4; ++r) {
            int o = oh + of * 16 + kq * 4 + r;
            float* orow = out + ((b * COUT + o) * H + ho) * W;
            #pragma unroll
            for (int pf = 0; pf < 2; ++pf) {
                int wo = wo0 + ph + pf * 16 + row16;
                orow[wo] = acc[of][pf][r];
            }
        }
    }
}

// ---------------------------------------------------------------------------
extern "C" void kernel_launch(void* const* d_in, const int* in_sizes, int n_in,
                              void* d_out, int out_size, void* d_ws, size_t ws_size,
                              hipStream_t stream)
{
    const float* x      = (const float*)d_in[0];
    const float* w_off  = (const float*)d_in[1];
    const float* b_off  = (const float*)d_in[2];
    const float* w_mask = (const float*)d_in[3];
    const float* b_mask = (const float*)d_in[4];
    const float* weight = (const float*)d_in[5];
    float* out   = (float*)d_out;

    float* offs  = (float*)d_ws;
    float* maskb = offs + OFFS_SZ;
    float* bcat  = maskb + MASK_SZ;
    short* wbf   = (short*)(bcat + 32);
    short* wcv   = wbf + WBF_SHORTS;

    prep_wcv<<<dim3((WCV_SHORTS + 255) / 256), 256, 0, stream>>>(
        w_off, b_off, w_mask, b_mask, wcv, bcat);
    prep_wbf<<<dim3((WBF_SHORTS + 255) / 256), 256, 0, stream>>>(weight, wbf);
    offmask6_kernel<<<dim3(1024), 256, 0, stream>>>(x, wcv, bcat, offs, maskb);
    deform8_kernel<<<dim3(1024), 256, 0, stream>>>(x, offs, maskb, wbf, out);
}

// Round 14
// 84.706 us; speedup vs baseline: 3.6353x; 1.0737x over previous
//
#include <hip/hip_runtime.h>
#include <math.h>

#define B 4
#define CIN 64
#define H 128
#define W 128
#define COUT 128
#define KK 9
#define HW (H*W)

#define WBF_COLS 640                 // 4 chunks x 160 (144 real + 16 zero)
#define WBF_SHORTS (COUT*WBF_COLS)
#define WCV_SHORTS (32*640)          // offmask conv weights, bf16, K-padded
#define LDK 168                      // LDS k-stride (shorts); 336B row stride

typedef __attribute__((ext_vector_type(8))) short short8;
typedef __attribute__((ext_vector_type(4))) float f32x4;
typedef __attribute__((ext_vector_type(2))) float f32x2;
typedef f32x2 __attribute__((aligned(4))) f32x2a;   // align-4 float2 load

// global->LDS DMA: 16B per lane, dest = wave-uniform base + lane*16.
#define GLDS16(g, l) __builtin_amdgcn_global_load_lds(                        \
    (__attribute__((address_space(1))) void*)(g),                             \
    (__attribute__((address_space(3))) void*)(l), 16, 0, 0)

__device__ __forceinline__ unsigned short f2bf(float f) {
    unsigned int u = __float_as_uint(f);
    u += 0x7fffu + ((u >> 16) & 1u);
    return (unsigned short)(u >> 16);
}

// ---------------------------------------------------------------------------
// prep_wcv: offmask conv weights -> bf16 wcv[f(32)][cb*160 + tap*16 + ci]
// (rows 27..31 and cols [144,160) zero). Also fills bcat (32 biases).
// ---------------------------------------------------------------------------
__global__ void prep_wcv(const float* __restrict__ w_off, const float* __restrict__ b_off,
                         const float* __restrict__ w_mask, const float* __restrict__ b_mask,
                         short* __restrict__ wcv, float* __restrict__ bcat)
{
    int idx = blockIdx.x * 256 + threadIdx.x;
    if (idx < WCV_SHORTS) {
        int f  = idx / 640;
        int kp = idx % 640;
        int cb = kp / 160, r = kp % 160;
        float v = 0.f;
        if (r < 144) {
            int tap = r >> 4;
            int c   = cb * 16 + (r & 15);
            if (f < 18)      v = w_off[(f * CIN + c) * 9 + tap];
            else if (f < 27) v = w_mask[((f - 18) * CIN + c) * 9 + tap];
        }
        wcv[idx] = (short)f2bf(v);
    }
    if (blockIdx.x == 0 && threadIdx.x < 32) {
        int f = threadIdx.x;
        float bv = 0.f;
        if (f < 18) bv = b_off[f];
        else if (f < 27) bv = b_mask[f - 18];
        bcat[f] = bv;
    }
}

// ---------------------------------------------------------------------------
// prep_wbf: einsum weights -> bf16, layout [o][cb*160 + tap*16 + ci];
// pad cols [144,160) per chunk are ZERO.
// ---------------------------------------------------------------------------
__global__ void prep_wbf(const float* __restrict__ wgt, short* __restrict__ wbf)
{
    int idx = blockIdx.x * 256 + threadIdx.x;
    if (idx >= WBF_SHORTS) return;
    int o  = idx / WBF_COLS;
    int kp = idx % WBF_COLS;
    int cb = kp / 160, r = kp % 160;
    float v = 0.f;
    if (r < 144) {
        int tap = r >> 4;
        int c   = cb * 16 + (r & 15);
        v = wgt[(o * CIN + c) * KK + tap];
    }
    wbf[idx] = (short)f2bf(v);
}

// ---------------------------------------------------------------------------
// fused2: phase A = offmask6's MFMA conv (validated R13), offs/mask kept in
// LDS (aliased into S); phase B = deform8 (validated R12/13) with metadata
// reading offs_l from LDS and pk-math bilinear (f32x2 v_pk_fma).
// Eliminates: offs/mask HBM round-trip, one launch + gap, duplicate
// prologue, metadata global-load stall. Sequential phase liveness keeps
// VGPRs ~64 (R10's spill failure mode was CONCURRENT live state).
// LDS: XW 13,824 + S 21,504 = 35,328 B -> 4 blocks/CU.
// XCD band swizzle; no chunk stagger.
// ---------------------------------------------------------------------------
__global__ __launch_bounds__(256, 2) void fused2_kernel(
    const float* __restrict__ x, const short* __restrict__ wcv,
    const short* __restrict__ wbf, const float* __restrict__ bcat,
    float* __restrict__ out)
{
    const int bid = blockIdx.x;
    const int T = (bid & 7) * 128 + (bid >> 3);
    const int wo0 = (T & 1) * 64;
    const int ho  = (T >> 1) & 127;
    const int b   = T >> 8;
    const int tid  = threadIdx.x;
    const int lane = tid & 63;
    const int wv   = tid >> 6;
    const int oh   = (wv & 1) * 64;
    const int ph   = (wv >> 1) * 32;
    const int row16 = lane & 15, kq = lane >> 4;

    __shared__ __align__(16) float XW[8 * 6 * 72];    // 13,824 B (A uses 1/2)
    __shared__ __align__(16) short S[64 * LDK];       // 21,504 B
    float* offs_l = (float*)S;                        // phase-A out: 27*64 f32

    const float* xb = x + (size_t)b * CIN * HW;

    // =======================================================================
    // Phase A: 27-filter conv via MFMA (M=32, N=64px, K=576).
    // =======================================================================
    int stA_goff[2];
    #pragma unroll
    for (int t = 0; t < 2; ++t) {
        int idx = tid + t * 256;
        int ci = idx / 54, rem = idx % 54, row = rem / 18, q = rem % 18;
        int ys = min(max(ho - 1 + row, 0), H - 1);
        int g0 = wo0 - 4 + q * 4;
        int g0c = min(max(g0, 0), W - 4);
        stA_goff[t] = ci * HW + ys * W + g0c;
    }
    auto stageA = [&](int h) {
        const float* base = xb + (size_t)h * 8 * HW;
        #pragma unroll
        for (int t = 0; t < 2; ++t) {
            if (tid + t * 256 < 432) {
                GLDS16(base + stA_goff[t], &XW[(tid + t * 256) * 4]);
            }
        }
    };

    if (tid < 128) {                      // zero K-pad [144,160)
        short8 z = {0,0,0,0,0,0,0,0};
        *(short8*)&S[(tid >> 1) * LDK + 144 + (tid & 1) * 8] = z;
    }
    stageA(0);                            // DMA in flight under metadata below

    int bidx[3];                           // im2col src offset; -1 = zero
    #pragma unroll
    for (int j = 0; j < 3; ++j) {
        bidx[j] = -1;
        int s = tid + j * 256;
        if (s < 576) {
            int k = s >> 6, p = s & 63;
            int ky = k / 3, kx = k % 3;
            bool ok = ((unsigned)(ho - 1 + ky) < (unsigned)H)
                   && ((unsigned)(wo0 + p - 1 + kx) < (unsigned)W);
            if (ok) bidx[j] = ky * 72 + (p + 3 + kx);
        }
    }
    // phase-B staging offsets (computed here to hide stageA(0))
    int stB_goff[4];
    #pragma unroll
    for (int t = 0; t < 4; ++t) {
        int idx = tid + t * 256;
        int ci = idx / 108, rem = idx % 108, row = rem / 18, q = rem % 18;
        int ys = min(max(ho - 2 + row, 0), H - 1);
        int g0 = wo0 - 4 + q * 4;
        int g0c = min(max(g0, 0), W - 4);
        stB_goff[t] = ci * HW + ys * W + g0c;
    }
    __syncthreads();                      // XW(A0) ready, pads zeroed

    f32x4 acc2[2];
    acc2[0] = (f32x4){0.f, 0.f, 0.f, 0.f};
    acc2[1] = (f32x4){0.f, 0.f, 0.f, 0.f};

    auto buildA = [&](int h) {
        #pragma unroll
        for (int j = 0; j < 3; ++j) {
            int s = tid + j * 256;
            if (s < 576) {
                int k = s >> 6, p = s & 63;
                short8 sv = {0,0,0,0,0,0,0,0};
                if (bidx[j] >= 0) {
                    #pragma unroll
                    for (int ci = 0; ci < 8; ++ci)
                        sv[ci] = (short)f2bf(XW[ci * 216 + bidx[j]]);
                }
                *(short8*)&S[p * LDK + k * 16 + (h & 1) * 8] = sv;
            }
        }
    };
    auto mfmaA = [&](int c) {
        #pragma unroll
        for (int ks = 0; ks < 5; ++ks) {
            short8 a0 = *(const short8*)(wcv + (row16)      * 640 + c * 160 + ks * 32 + kq * 8);
            short8 a1 = *(const short8*)(wcv + (16 + row16) * 640 + c * 160 + ks * 32 + kq * 8);
            short8 bfr = *(const short8*)&S[(wv * 16 + row16) * LDK + ks * 32 + kq * 8];
            acc2[0] = __builtin_amdgcn_mfma_f32_16x16x32_bf16(a0, bfr, acc2[0], 0, 0, 0);
            acc2[1] = __builtin_amdgcn_mfma_f32_16x16x32_bf16(a1, bfr, acc2[1], 0, 0, 0);
        }
    };

    buildA(0); __syncthreads();
    stageA(1); __syncthreads(); buildA(1); __syncthreads();
    #pragma unroll 1
    for (int c = 0; c < 3; ++c) {
        stageA(2 * c + 2);
        mfmaA(c);
        __syncthreads();
        buildA(2 * c + 2);
        __syncthreads();
        stageA(2 * c + 3);
        __syncthreads();
        buildA(2 * c + 3);
        __syncthreads();
    }
    mfmaA(3);
    __syncthreads();                      // all S reads done -> S reusable

    // conv epilogue: bias + sigmoid -> offs_l (LDS, aliases S)
    {
        const int pxl = wv * 16 + row16;
        #pragma unroll
        for (int of = 0; of < 2; ++of) {
            #pragma unroll
            for (int r = 0; r < 4; ++r) {
                int f = of * 16 + kq * 4 + r;
                if (f < 27) {
                    float v = acc2[of][r] + bcat[f];
                    if (f >= 18) v = 1.f / (1.f + expf(-v));
                    offs_l[f * 64 + pxl] = v;
                }
            }
        }
    }
    __syncthreads();                      // offs_l visible

    // =======================================================================
    // Phase B: deform sample + MFMA einsum.
    // =======================================================================
    auto stageB = [&](int h) {
        const float* base = xb + (size_t)h * 8 * HW;
        #pragma unroll
        for (int t = 0; t < 4; ++t) {
            if (tid + t * 256 < 864) {
                GLDS16(base + stB_goff[t], &XW[(tid + t * 256) * 4]);
            }
        }
    };

    stageB(0);                            // DMA hides under metadata below

    int   moff[3][2];
    int   lidx0[3], lidx1[3];
    f32x2 wAB[3], wCD[3];
    #pragma unroll
    for (int j = 0; j < 3; ++j) {
        moff[j][0] = 0; moff[j][1] = 0;
        lidx0[j] = -1; lidx1[j] = 0;
        wAB[j] = (f32x2){0.f, 0.f}; wCD[j] = (f32x2){0.f, 0.f};
        int s = tid + j * 256;
        if (s < 576) {
            int k = s >> 6, p = s & 63;
            int wo = wo0 + p;
            int ky = k / 3, kx = k % 3;
            float dy = offs_l[(2 * k) * 64 + p];
            float dx = offs_l[(2 * k + 1) * 64 + p];
            float mk = offs_l[(18 + k) * 64 + p];
            float py  = (float)(ho - 1 + ky) + dy;
            float pxf = (float)(wo - 1 + kx) + dx;
            float fy = floorf(py), fx = floorf(pxf);
            float ly = py - fy, lx = pxf - fx;
            int y0 = (int)fy, x0 = (int)fx;
            int y1 = y0 + 1,  x1 = x0 + 1;
            bool vy0 = (y0 >= 0) && (y0 < H);
            bool vy1 = (y1 >= 0) && (y1 < H);
            bool vx0 = (x0 >= 0) && (x0 < W);
            bool vx1 = (x1 >= 0) && (x1 < W);
            float w0 = (vy0 && vx0) ? (1.f - ly) * (1.f - lx) * mk : 0.f;
            float w1 = (vy0 && vx1) ? (1.f - ly) * lx * mk : 0.f;
            float w2 = (vy1 && vx0) ? ly * (1.f - lx) * mk : 0.f;
            float w3 = (vy1 && vx1) ? ly * lx * mk : 0.f;
            int lc = min(max(x0, 0), W - 2);
            bool sel = (x0 == lc);
            int r0 = min(max(y0, 0), H - 1);
            int r1 = min(max(y1, 0), H - 1);
            moff[j][0] = (r0 * W + lc) * 4;
            moff[j][1] = (r1 * W + lc) * 4;
            wAB[j].x = sel ? w0 : w1;  wAB[j].y = sel ? w1 : w0;
            wCD[j].x = sel ? w2 : w3;  wCD[j].y = sel ? w3 : w2;
            int u0 = r0 - (ho - 2);
            int u1 = r1 - (ho - 2);
            int vvv = lc - (wo0 - 4);
            bool fastp = ((unsigned)u0 < 6u) && ((unsigned)u1 < 6u)
                       && ((unsigned)vvv < 71u);
            lidx1[j] = u1 * 72 + vvv;
            lidx0[j] = fastp ? (u0 * 72 + vvv) : -1;
        }
    }
    __syncthreads();                      // offs_l reads done; XW(B0) ready

    if (tid < 128) {                      // re-zero pads clobbered by offs_l
        short8 z = {0,0,0,0,0,0,0,0};
        *(short8*)&S[(tid >> 1) * LDK + 144 + (tid & 1) * 8] = z;
    }

    f32x4 acc[4][2];
    #pragma unroll
    for (int i = 0; i < 4; ++i)
        #pragma unroll
        for (int j = 0; j < 2; ++j)
            acc[i][j] = (f32x4){0.f, 0.f, 0.f, 0.f};

    auto sampleB = [&](int h) {
        #pragma unroll
        for (int j = 0; j < 3; ++j) {
            int s = tid + j * 256;
            if (s < 576) {
                int k = s >> 6, p = s & 63;
                float va[8];
                f32x2 wab = wAB[j], wcd = wCD[j];
                if (lidx0[j] >= 0) {
                    int l0 = lidx0[j], l1 = lidx1[j];
                    #pragma unroll
                    for (int ci = 0; ci < 8; ++ci) {
                        const float* bp = &XW[ci * 432];
                        f32x2 A  = *(const f32x2a*)(bp + l0);   // ds_read2_b32
                        f32x2 Bv = *(const f32x2a*)(bp + l1);
                        f32x2 t = A * wab + Bv * wcd;           // v_pk_fma_f32
                        va[ci] = t.x + t.y;
                    }
                } else {
                    #pragma unroll
                    for (int ci = 0; ci < 8; ++ci) {
                        const char* pc = (const char*)(xb + (size_t)(h * 8 + ci) * HW);
                        f32x2 A  = *(const f32x2a*)(pc + moff[j][0]);
                        f32x2 Bv = *(const f32x2a*)(pc + moff[j][1]);
                        f32x2 t = A * wab + Bv * wcd;
                        va[ci] = t.x + t.y;
                    }
                }
                short8 sv;
                #pragma unroll
                for (int ci = 0; ci < 8; ++ci) sv[ci] = (short)f2bf(va[ci]);
                *(short8*)&S[p * LDK + k * 16 + (h & 1) * 8] = sv;
            }
        }
    };

    auto mfmaB = [&](int c) {
        #pragma unroll
        for (int ks = 0; ks < 5; ++ks) {
            short8 a[4];
            #pragma unroll
            for (int of = 0; of < 4; ++of) {
                int o = oh + of * 16 + row16;
                a[of] = *(const short8*)(wbf + o * WBF_COLS + c * 160 + ks * 32 + kq * 8);
            }
            #pragma unroll
            for (int pf = 0; pf < 2; ++pf) {
                int p = ph + pf * 16 + row16;
                short8 bfr = *(const short8*)&S[p * LDK + ks * 32 + kq * 8];
                #pragma unroll
                for (int of = 0; of < 4; ++of)
                    acc[of][pf] = __builtin_amdgcn_mfma_f32_16x16x32_bf16(
                        a[of], bfr, acc[of][pf], 0, 0, 0);
            }
        }
    };

    sampleB(0); __syncthreads();
    stageB(1); __syncthreads(); sampleB(1); __syncthreads();
    #pragma unroll 1
    for (int c = 0; c < 3; ++c) {
        stageB(2 * c + 2);     // DMA in flight under MFMA below
        mfmaB(c);
        __syncthreads();
        sampleB(2 * c + 2);
        __syncthreads();
        stageB(2 * c + 3);
        __syncthreads();
        sampleB(2 * c + 3);
        __syncthreads();
    }
    mfmaB(3);

    // ---- store: C/D layout col(px)=lane&15, row(o)=(lane>>4)*4+r ----
    #pragma unroll
    for (int of = 0; of < 4; ++of) {
        #pragma unroll
        for (int r = 0; r < 4; ++r) {
            int o = oh + of * 16 + kq * 4 + r;
            float* orow = out + ((b * COUT + o) * H + ho) * W;
            #pragma unroll
            for (int pf = 0; pf < 2; ++pf) {
                int wo = wo0 + ph + pf * 16 + row16;
                orow[wo] = acc[of][pf][r];
            }
        }
    }
}

// ---------------------------------------------------------------------------
extern "C" void kernel_launch(void* const* d_in, const int* in_sizes, int n_in,
                              void* d_out, int out_size, void* d_ws, size_t ws_size,
                              hipStream_t stream)
{
    const float* x      = (const float*)d_in[0];
    const float* w_off  = (const float*)d_in[1];
    const float* b_off  = (const float*)d_in[2];
    const float* w_mask = (const float*)d_in[3];
    const float* b_mask = (const float*)d_in[4];
    const float* weight = (const float*)d_in[5];
    float* out   = (float*)d_out;

    float* bcat  = (float*)d_ws;
    short* wbf   = (short*)(bcat + 32);
    short* wcv   = wbf + WBF_SHORTS;

    prep_wcv<<<dim3((WCV_SHORTS + 255) / 256), 256, 0, stream>>>(
        w_off, b_off, w_mask, b_mask, wcv, bcat);
    prep_wbf<<<dim3((WBF_SHORTS + 255) / 256), 256, 0, stream>>>(weight, wbf);
    fused2_kernel<<<dim3(1024), 256, 0, stream>>>(x, wcv, wbf, bcat, out);
}